// Round 22
// baseline (191.336 us; speedup 1.0000x reference)
//
#include <hip/hip_runtime.h>
#include <hip/hip_bf16.h>

typedef __bf16 bf16x8 __attribute__((ext_vector_type(8)));
typedef __bf16 bf16x4 __attribute__((ext_vector_type(4)));
typedef float f32x4 __attribute__((ext_vector_type(4)));
typedef float f32x16 __attribute__((ext_vector_type(16)));

#define NB 4
#define NS 2048
#define ND 1024
#define NH 16
#define NDH 64
#define NM (NB*NS)   // 8192

#define MFMA(a,b,c)   __builtin_amdgcn_mfma_f32_16x16x32_bf16((a),(b),(c),0,0,0)
#define MFMA32(a,b,c) __builtin_amdgcn_mfma_f32_32x32x16_bf16((a),(b),(c),0,0,0)

__device__ __forceinline__ void gload16(const void* g, void* l) {
    __builtin_amdgcn_global_load_lds(
        (const __attribute__((address_space(1))) void*)(g),
        (__attribute__((address_space(3))) void*)(l),
        16, 0, 0);
}

__device__ __forceinline__ unsigned cvt_pk_bf16(float lo, float hi) {
    unsigned w;
    asm("v_cvt_pk_bf16_f32 %0, %1, %2" : "=v"(w) : "v"(lo), "v"(hi));
    return w;
}
__device__ __forceinline__ float fmax3(float a, float b, float c) {
    float d;
    asm("v_max3_f32 %0, %1, %2, %3" : "=v"(d) : "v"(a), "v"(b), "v"(c));
    return d;
}
// swap a's upper 32 lanes with b's lower 32 lanes (in place)
#define PLSWAP(a, b) asm("v_permlane32_swap_b32 %0, %1" : "+v"(a), "+v"(b))

// fused 4-weight cast: blockIdx.y selects which weight
__global__ __launch_bounds__(256) void cast4w(
    const float* __restrict__ w0, const float* __restrict__ w1,
    const float* __restrict__ w2, const float* __restrict__ w3,
    __bf16* __restrict__ o0, __bf16* __restrict__ o1,
    __bf16* __restrict__ o2, __bf16* __restrict__ o3) {
    const int z = blockIdx.y;
    const float* in  = (z == 0) ? w0 : (z == 1) ? w1 : (z == 2) ? w2 : w3;
    __bf16*      out = (z == 0) ? o0 : (z == 1) ? o1 : (z == 2) ? o2 : o3;
    int i = (blockIdx.x * 256 + threadIdx.x) * 4;
    float4 v = *(const float4*)(in + i);
    bf16x4 o;
    o[0] = (__bf16)v.x; o[1] = (__bf16)v.y; o[2] = (__bf16)v.z; o[3] = (__bf16)v.w;
    *(bf16x4*)(out + i) = o;
}

// -------- GEMM 128x256, BK=64, 512 thr, fused-cast A (MODE 0) ---------------
// 8 waves (2M x 4N), per-wave 64x64, single-buffer LDS (48 KB -> 2-3
// blocks/CU), XOR-swizzled rows (LDS unit k of row r holds global unit
// k^(r&7); read side XORs the same), 2-barrier loop.
// MODE 0: A is x in FP32 -- staged via registers: float4 loads issued right
//   after the tile-visible barrier (latency hides under 32 MFMAs), converted
//   with v_cvt_pk_bf16_f32, ds_write_b128 into the swizzled layout. This
//   fuses the former cast4 kernel (48 MB traffic + launch) into the GEMM.
//   z=0 -> Q (scaled 1/8*log2e), z=1 -> K, z=2 -> V^T (LDS-transpose store).
// MODE 1: A bf16 via global_load_lds; C fp32 row-major [M,N].
template<int MODE>
__global__ __launch_bounds__(512) void gemmfs(
    const float* __restrict__ Xf, const __bf16* __restrict__ Abf,
    const __bf16* __restrict__ W0, const __bf16* __restrict__ W1,
    const __bf16* __restrict__ W2,
    __bf16* __restrict__ O0, __bf16* __restrict__ O1, __bf16* __restrict__ O2,
    float* __restrict__ Cf)
{
    __shared__ alignas(16) __bf16 As[128*64];   // 16 KB
    __shared__ alignas(16) __bf16 Bs[256*64];   // 32 KB

    const int tid  = threadIdx.x;
    const int wave = tid >> 6, lane = tid & 63;
    const int l16  = lane & 15, lq = lane >> 4;
    const int bm = blockIdx.x * 128;
    const int bn = blockIdx.y * 256;
    const int z  = (MODE == 0) ? blockIdx.z : 0;
    const __bf16* __restrict__ Bw =
        (MODE == 0) ? ((z == 0) ? W0 : (z == 1) ? W1 : W2) : W0;

    const int wr = (wave >> 2) * 64;     // 2 M-waves
    const int wc = (wave & 3) * 64;      // 4 N-waves

    f32x4 acc[4][4];
    #pragma unroll
    for (int i = 0; i < 4; i++)
        #pragma unroll
        for (int j = 0; j < 4; j++)
            acc[i][j] = (f32x4){0.f, 0.f, 0.f, 0.f};

    // staging geometry: row tid>>3 (+64c), 16B-unit tid&7, source pre-XOR'd
    const int arow = tid >> 3;
    const int au   = (tid & 7) ^ (arow & 7);    // row&7 invariant under +64
    // B (bf16, gload16): 256 rows x 8 units = 2048 units, 4 per thread
    const __bf16* Bg0 = Bw + (size_t)(bn + arow) * ND + au * 8;
    const __bf16* Bg1 = Bg0 + (size_t)64 * ND;
    const __bf16* Bg2 = Bg0 + (size_t)128 * ND;
    const __bf16* Bg3 = Bg0 + (size_t)192 * ND;
    // A MODE 0 (fp32 reg-staged): 2 units/thread -> 4 float4 loads
    const float* Xa0 = (MODE == 0) ? Xf + (size_t)(bm + arow) * ND + au * 8 : nullptr;
    const float* Xa1 = (MODE == 0) ? Xa0 + (size_t)64 * ND : nullptr;
    // A MODE 1 (bf16 gload16): 2 units/thread
    const __bf16* Ag0 = (MODE == 1) ? Abf + (size_t)(bm + arow) * ND + au * 8 : nullptr;
    const __bf16* Ag1 = (MODE == 1) ? Ag0 + (size_t)64 * ND : nullptr;

    const int asw = l16 & 7;   // read-side swizzle (frag row & 7)

    f32x4 ar[4];
    if (MODE == 0) {           // prologue: tile 0 A regs
        ar[0] = *(const f32x4*)(Xa0);
        ar[1] = *(const f32x4*)(Xa0 + 4);
        ar[2] = *(const f32x4*)(Xa1);
        ar[3] = *(const f32x4*)(Xa1 + 4);
    }

    #pragma unroll 1
    for (int t = 0; t < 16; ++t) {
        const int k0 = t * 64;
        __syncthreads();                       // prior tile's reads complete
        if (MODE == 0) {
            uint4 wA0 = {cvt_pk_bf16(ar[0][0], ar[0][1]), cvt_pk_bf16(ar[0][2], ar[0][3]),
                         cvt_pk_bf16(ar[1][0], ar[1][1]), cvt_pk_bf16(ar[1][2], ar[1][3])};
            uint4 wA1 = {cvt_pk_bf16(ar[2][0], ar[2][1]), cvt_pk_bf16(ar[2][2], ar[2][3]),
                         cvt_pk_bf16(ar[3][0], ar[3][1]), cvt_pk_bf16(ar[3][2], ar[3][3])};
            *(uint4*)(As + tid * 8)         = wA0;
            *(uint4*)(As + (tid + 512) * 8) = wA1;
        } else {
            gload16(Ag0 + k0, As + tid * 8);
            gload16(Ag1 + k0, As + (tid + 512) * 8);
        }
        gload16(Bg0 + k0, Bs + tid * 8);
        gload16(Bg1 + k0, Bs + (tid + 512) * 8);
        gload16(Bg2 + k0, Bs + (tid + 1024) * 8);
        gload16(Bg3 + k0, Bs + (tid + 1536) * 8);
        asm volatile("s_waitcnt vmcnt(0)" ::: "memory");
        __syncthreads();                       // tile visible

        if (MODE == 0 && t + 1 < 16) {         // next A -> regs (hides under MFMA)
            ar[0] = *(const f32x4*)(Xa0 + k0 + 64);
            ar[1] = *(const f32x4*)(Xa0 + k0 + 68);
            ar[2] = *(const f32x4*)(Xa1 + k0 + 64);
            ar[3] = *(const f32x4*)(Xa1 + k0 + 68);
        }

        #pragma unroll
        for (int kk = 0; kk < 2; kk++) {
            bf16x8 af[4], bfr[4];
            #pragma unroll
            for (int i = 0; i < 4; i++)
                af[i] = *(const bf16x8*)(As + (wr + i*16 + l16) * 64
                                          + ((kk*4 + lq) ^ asw) * 8);
            #pragma unroll
            for (int j = 0; j < 4; j++)
                bfr[j] = *(const bf16x8*)(Bs + (wc + j*16 + l16) * 64
                                           + ((kk*4 + lq) ^ asw) * 8);
            __builtin_amdgcn_s_setprio(1);
            #pragma unroll
            for (int i = 0; i < 4; i++)
                #pragma unroll
                for (int j = 0; j < 4; j++)
                    acc[i][j] = MFMA(af[i], bfr[j], acc[i][j]);
            __builtin_amdgcn_s_setprio(0);
        }
    }

    if (MODE == 0 && z == 2) {
        // ---- V^T epilogue: LDS transpose (reuse As), coalesced stores ----
        __bf16* T = As;
        const int TP = 136;                    // 32 cols x 128 rows, padded
        #pragma unroll 1
        for (int c = 0; c < 8; ++c) {          // 8 chunks of 32 n-cols
            __syncthreads();
            #pragma unroll
            for (int j = 0; j < 4; j++) {
                if (((wc + j * 16) >> 5) != c) continue;
                #pragma unroll
                for (int i = 0; i < 4; i++)
                    #pragma unroll
                    for (int r = 0; r < 4; r++) {
                        int row = wr + i*16 + lq*4 + r;       // m-local (s)
                        int col = wc + j*16 + l16 - c*32;     // chunk-local n
                        T[col * TP + row] = (__bf16)acc[i][j][r];
                    }
            }
            __syncthreads();
            {
                int trow = tid >> 4, tu = tid & 15; // col 0..31, 16B unit
                int gcol = bn + c*32 + trow;        // global n = h*64+dh
                int gs   = bm + tu * 8;             // global m = b*S + s
                bf16x8 val = *(const bf16x8*)&T[trow * TP + tu * 8];
                int hh = gcol >> 6, dh = gcol & 63;
                *(bf16x8*)&O2[(((size_t)(gs >> 11) * NH + hh) * NDH + dh) * NS
                              + (gs & 2047)] = val;
            }
        }
        return;
    }

    #pragma unroll
    for (int i = 0; i < 4; i++) {
        #pragma unroll
        for (int j = 0; j < 4; j++) {
            #pragma unroll
            for (int r = 0; r < 4; r++) {
                int row = bm + wr + i*16 + lq*4 + r;   // m index (b*S + s)
                int col = bn + wc + j*16 + l16;        // n index (d_out)
                float v = acc[i][j][r];
                if (MODE == 1) {
                    Cf[(size_t)row * ND + col] = v;
                } else {
                    if (z == 0) v *= 0.1803368801111204f;  // 1/8 * log2(e)
                    int b = row >> 11, s = row & 2047;
                    int h = col >> 6,  dh = col & 63;
                    __bf16* dst = (z == 0) ? O0 : O1;
                    dst[(((size_t)b*NH + h)*NS + s)*NDH + dh] = (__bf16)v;
                }
            }
        }
    }
}

// ------- causal flash attention (round-21 best: T14 reg-staged, ~86.6 us) ---
__global__ __launch_bounds__(256) void attn_rs(
    const __bf16* __restrict__ Q, const __bf16* __restrict__ K,
    const __bf16* __restrict__ Vt, __bf16* __restrict__ Oa)
{
    __shared__ alignas(16) __bf16 Ks[32*64];   // [kv][dh], source-swizzled
    __shared__ alignas(16) __bf16 Vs[64*32];   // [d][kv],  source-swizzled
    __shared__ float Fs[4][32];

    const int tid  = threadIdx.x;
    const int wave = tid >> 6, lane = tid & 63;
    const int qq   = lane & 31, hi = lane >> 5;

    const int bid = blockIdx.x;                          // 0..1023
    const int jg  = 15 - (bid >> 6);                     // LPT: long first
    const int bh  = (bid & 7) * 8 + ((bid >> 3) & 7);    // XCD-pinned head
    const int j   = 4 * jg + wave;                       // wave's q-block
    const int q0  = 32 * j;
    const int nt  = 4 * jg + 4;                          // staged tiles/block

    const int b = bh >> 4, h = bh & 15;
    const size_t qkb = (size_t)bh * NS * NDH;   // Q,K  [bh][s][dh]
    const size_t vbb = (size_t)bh * NDH * NS;   // Vt   [bh][dh][s]
    float* Fw = Fs[wave];

    // Q fragments (B-operand): col q = qq, k = c*16 + hi*8
    bf16x8 qf[4];
    {
        const __bf16* qr = Q + qkb + (size_t)(q0 + qq) * NDH + hi * 8;
        #pragma unroll
        for (int c = 0; c < 4; c++) qf[c] = *(const bf16x8*)(qr + c * 16);
    }

    f32x16 o0 = (f32x16)0.f, o1 = (f32x16)0.f;  // row q=crow(r), col d=qq(+32)
    float mr = -__builtin_inff(), lsum = 0.f;

    // staging geometry (per thread, one 16B chunk of K and one of V per tile)
    const int kr = tid >> 3, ku = tid & 7;               // K row, LDS unit
    const int vd = tid >> 2, vu = tid & 3;               // V row, LDS unit
    const __bf16* ksrc = K  + qkb + (size_t)kr * NDH + (size_t)((ku ^ (kr & 7)) * 8);
    const __bf16* vsrc = Vt + vbb + (size_t)vd * NS  + (size_t)((vu ^ ((vd >> 1) & 3)) * 8);
    __bf16* kdst = Ks + tid * 8;
    __bf16* vdst = Vs + tid * 8;

    const int vsw = (qq >> 1) & 3;   // V read-side swizzle (same for row qq+32)

    // prologue: load tile 0 into staging registers
    bf16x8 kreg = *(const bf16x8*)ksrc;
    bf16x8 vreg = *(const bf16x8*)vsrc;
    ksrc += 32 * NDH; vsrc += 32;

    #pragma unroll 1
    for (int t = 0; t < nt; ++t) {
        __syncthreads();                 // prior reads done; loads aged
        *(bf16x8*)kdst = kreg;           // write tile t to LDS
        *(bf16x8*)vdst = vreg;
        __syncthreads();                 // tile t visible to all waves

        if (t + 1 < nt) {                // issue tile t+1 loads -> regs
            kreg = *(const bf16x8*)ksrc; // (latency hides under compute)
            vreg = *(const bf16x8*)vsrc;
            ksrc += 32 * NDH; vsrc += 32;
        }

        if (t <= j) {
            // fragment reads (swizzled, conflict-free)
            bf16x8 kf[4], vf[4];
            #pragma unroll
            for (int c = 0; c < 4; c++)
                kf[c] = *(const bf16x8*)(Ks + qq * 64 + ((2 * c + hi) ^ (qq & 7)) * 8);
            vf[0] = *(const bf16x8*)(Vs + qq * 32        + ((hi)     ^ vsw) * 8);
            vf[1] = *(const bf16x8*)(Vs + qq * 32        + ((2 + hi) ^ vsw) * 8);
            vf[2] = *(const bf16x8*)(Vs + (qq + 32) * 32 + ((hi)     ^ vsw) * 8);
            vf[3] = *(const bf16x8*)(Vs + (qq + 32) * 32 + ((2 + hi) ^ vsw) * 8);

            f32x16 s = (f32x16)0.f;
            __builtin_amdgcn_s_setprio(1);
            #pragma unroll
            for (int c = 0; c < 4; c++) s = MFMA32(kf[c], qf[c], s);
            __builtin_amdgcn_s_setprio(0);

            if (t == j) {   // diagonal tile: kv0 == q0
                #pragma unroll
                for (int r = 0; r < 16; r++) {
                    const int crow = (r & 3) + 8 * (r >> 2) + 4 * hi;
                    if (crow > qq) s[r] = -__builtin_inff();
                }
            }

            // max of this lane's 16 scores via v_max3 tree (8 ops)
            float a0 = fmax3(s[0],  s[1],  s[2]);
            float a1 = fmax3(s[3],  s[4],  s[5]);
            float a2 = fmax3(s[6],  s[7],  s[8]);
            float a3 = fmax3(s[9],  s[10], s[11]);
            float a4 = fmax3(s[12], s[13], s[14]);
            float tm = fmaxf(fmax3(a0, a1, a2), fmax3(a3, a4, s[15]));

            if (__any(tm > mr + 8.f)) {
                float rowm = fmaxf(tm, __shfl_xor(tm, 32));
                float mnew = fmaxf(mr, rowm);
                float fac  = exp2f(mr - mnew);
                mr = mnew; lsum *= fac;
                if (lane < 32) Fw[qq] = fac;
                f32x4 f0 = *(const f32x4*)&Fw[4 * hi];
                f32x4 f1 = *(const f32x4*)&Fw[8 + 4 * hi];
                f32x4 f2 = *(const f32x4*)&Fw[16 + 4 * hi];
                f32x4 f3 = *(const f32x4*)&Fw[24 + 4 * hi];
                #pragma unroll
                for (int i = 0; i < 4; i++) {
                    o0[i]      *= f0[i]; o1[i]      *= f0[i];
                    o0[4 + i]  *= f1[i]; o1[4 + i]  *= f1[i];
                    o0[8 + i]  *= f2[i]; o1[8 + i]  *= f2[i];
                    o0[12 + i] *= f3[i]; o1[12 + i] *= f3[i];
                }
            }

            float pv[16]; float psum = 0.f;
            #pragma unroll
            for (int r = 0; r < 16; r++) { pv[r] = exp2f(s[r] - mr); psum += pv[r]; }
            lsum += psum;

            unsigned w0 = cvt_pk_bf16(pv[0],  pv[1]);
            unsigned w1 = cvt_pk_bf16(pv[2],  pv[3]);
            unsigned w2 = cvt_pk_bf16(pv[4],  pv[5]);
            unsigned w3 = cvt_pk_bf16(pv[6],  pv[7]);
            unsigned w4 = cvt_pk_bf16(pv[8],  pv[9]);
            unsigned w5 = cvt_pk_bf16(pv[10], pv[11]);
            unsigned w6 = cvt_pk_bf16(pv[12], pv[13]);
            unsigned w7 = cvt_pk_bf16(pv[14], pv[15]);
            PLSWAP(w0, w2); PLSWAP(w1, w3);
            PLSWAP(w4, w6); PLSWAP(w5, w7);
            bf16x8 pa0 = __builtin_bit_cast(bf16x8, (uint4){w0, w1, w2, w3});
            bf16x8 pa1 = __builtin_bit_cast(bf16x8, (uint4){w4, w5, w6, w7});

            __builtin_amdgcn_s_setprio(1);
            o0 = MFMA32(pa0, vf[0], o0);
            o0 = MFMA32(pa1, vf[1], o0);
            o1 = MFMA32(pa0, vf[2], o1);
            o1 = MFMA32(pa1, vf[3], o1);
            __builtin_amdgcn_s_setprio(0);
        }
    }

    // merge pair-halves of lsum; transport 1/l to o-layout; store
    lsum += __shfl_xor(lsum, 32);
    if (lane < 32) Fw[qq] = 1.f / lsum;
    f32x4 i0 = *(const f32x4*)&Fw[4 * hi];
    f32x4 i1 = *(const f32x4*)&Fw[8 + 4 * hi];
    f32x4 i2 = *(const f32x4*)&Fw[16 + 4 * hi];
    f32x4 i3 = *(const f32x4*)&Fw[24 + 4 * hi];
    __bf16* ob = Oa + ((size_t)b * NS + q0) * ND + h * 64 + qq;
    #pragma unroll
    for (int g2 = 0; g2 < 4; g2++) {
        f32x4 iv = (g2 == 0) ? i0 : (g2 == 1) ? i1 : (g2 == 2) ? i2 : i3;
        #pragma unroll
        for (int i = 0; i < 4; i++) {
            const int row = 8 * g2 + 4 * hi + i;
            ob[(size_t)row * ND]      = (__bf16)(o0[4 * g2 + i] * iv[i]);
            ob[(size_t)row * ND + 32] = (__bf16)(o1[4 * g2 + i] * iv[i]);
        }
    }
}

extern "C" void kernel_launch(void* const* d_in, const int* in_sizes, int n_in,
                              void* d_out, int out_size, void* d_ws, size_t ws_size,
                              hipStream_t stream) {
    const float* x  = (const float*)d_in[0];
    const float* wq = (const float*)d_in[1];
    const float* wk = (const float*)d_in[2];
    const float* wv = (const float*)d_in[3];
    const float* wo = (const float*)d_in[4];
    char* ws = (char*)d_ws;

    __bf16* wqb = (__bf16*)(ws + (16ull << 20));      //  2 MB
    __bf16* wkb = (__bf16*)(ws + (18ull << 20));
    __bf16* wvb = (__bf16*)(ws + (20ull << 20));
    __bf16* wob = (__bf16*)(ws + (22ull << 20));
    __bf16* Qb  = (__bf16*)(ws + (24ull << 20));      // 16 MB [B,H,S,Dh]
    __bf16* Kb  = (__bf16*)(ws + (40ull << 20));      // 16 MB [B,H,S,Dh]
    __bf16* Vtb = (__bf16*)(ws + (56ull << 20));      // 16 MB [B,H,Dh,S]
    __bf16* Ab  = (__bf16*)(ws + (72ull << 20));      // 16 MB [B,S,D]
    float* out  = (float*)d_out;

    cast4w<<<dim3(ND * ND / 1024, 4), 256, 0, stream>>>(
        wq, wk, wv, wo, wqb, wkb, wvb, wob);

    gemmfs<0><<<dim3(NM/128, ND/256, 3), 512, 0, stream>>>(
        x, nullptr, wqb, wkb, wvb, Qb, Kb, Vtb, nullptr);

    attn_rs<<<dim3(1024), 256, 0, stream>>>(Qb, Kb, Vtb, Ab);

    gemmfs<1><<<dim3(NM/128, ND/256), 512, 0, stream>>>(
        nullptr, Ab, wob, nullptr, nullptr, nullptr, nullptr, nullptr, out);
}

// Round 23
// 179.298 us; speedup vs baseline: 1.0671x; 1.0671x over previous
//
#include <hip/hip_runtime.h>
#include <hip/hip_bf16.h>

typedef __bf16 bf16x8 __attribute__((ext_vector_type(8)));
typedef __bf16 bf16x4 __attribute__((ext_vector_type(4)));
typedef float f32x4 __attribute__((ext_vector_type(4)));
typedef float f32x16 __attribute__((ext_vector_type(16)));

#define NB 4
#define NS 2048
#define ND 1024
#define NH 16
#define NDH 64
#define NM (NB*NS)   // 8192

#define MFMA(a,b,c)   __builtin_amdgcn_mfma_f32_16x16x32_bf16((a),(b),(c),0,0,0)
#define MFMA32(a,b,c) __builtin_amdgcn_mfma_f32_32x32x16_bf16((a),(b),(c),0,0,0)

__device__ __forceinline__ void gload16(const void* g, void* l) {
    __builtin_amdgcn_global_load_lds(
        (const __attribute__((address_space(1))) void*)(g),
        (__attribute__((address_space(3))) void*)(l),
        16, 0, 0);
}

__device__ __forceinline__ unsigned cvt_pk_bf16(float lo, float hi) {
    unsigned w;
    asm("v_cvt_pk_bf16_f32 %0, %1, %2" : "=v"(w) : "v"(lo), "v"(hi));
    return w;
}
__device__ __forceinline__ float fmax3(float a, float b, float c) {
    float d;
    asm("v_max3_f32 %0, %1, %2, %3" : "=v"(d) : "v"(a), "v"(b), "v"(c));
    return d;
}
// swap a's upper 32 lanes with b's lower 32 lanes (in place)
#define PLSWAP(a, b) asm("v_permlane32_swap_b32 %0, %1" : "+v"(a), "+v"(b))

// ---------------- merged cast: x (8x2^20 elems) + 4 weights (2^20 each) ----
// Segment boundaries are 2^20-aligned, so segment choice is block-uniform.
__global__ __launch_bounds__(256) void cast_all(
    const float* __restrict__ x,
    const float* __restrict__ w0, const float* __restrict__ w1,
    const float* __restrict__ w2, const float* __restrict__ w3,
    __bf16* __restrict__ xb,
    __bf16* __restrict__ o0, __bf16* __restrict__ o1,
    __bf16* __restrict__ o2, __bf16* __restrict__ o3)
{
    size_t i = ((size_t)blockIdx.x * 256 + threadIdx.x) * 4;
    const int seg = (int)(i >> 20);
    const float* in; __bf16* out; size_t base;
    if (seg < 8) { in = x; out = xb; base = i; }
    else {
        const int z = seg - 8;
        in  = (z == 0) ? w0 : (z == 1) ? w1 : (z == 2) ? w2 : w3;
        out = (z == 0) ? o0 : (z == 1) ? o1 : (z == 2) ? o2 : o3;
        base = i & 1048575;
    }
    float4 v = *(const float4*)(in + base);
    bf16x4 o;
    o[0] = (__bf16)v.x; o[1] = (__bf16)v.y; o[2] = (__bf16)v.z; o[3] = (__bf16)v.w;
    *(bf16x4*)(out + base) = o;
}

// ---------------- 8-phase-style pipelined GEMM (round-19/21 best) -----------
// 128x256 tile, BK=64, 512 threads = 8 waves (2M x 4N), per-wave 64x64.
// Double-buffered LDS (96KB), XOR-swizzled rows, counted vmcnt(6), raw
// barriers, two phases per K-tile with setprio'd MFMA clusters.
// MODE 0: z=0 -> Q (scaled 1/8*log2e), z=1 -> K, z=2 -> V^T (LDS transpose).
// MODE 1: C fp32 row-major [M,N].
template<int MODE>
__global__ __launch_bounds__(512) void gemm8p(
    const __bf16* __restrict__ A,
    const __bf16* __restrict__ W0, const __bf16* __restrict__ W1,
    const __bf16* __restrict__ W2,
    __bf16* __restrict__ O0, __bf16* __restrict__ O1, __bf16* __restrict__ O2,
    float* __restrict__ Cf)
{
    __shared__ alignas(16) __bf16 As0[128*64];
    __shared__ alignas(16) __bf16 As1[128*64];
    __shared__ alignas(16) __bf16 Bs0[256*64];
    __shared__ alignas(16) __bf16 Bs1[256*64];

    const int tid  = threadIdx.x;
    const int wave = tid >> 6, lane = tid & 63;
    const int l16  = lane & 15, lq = lane >> 4;
    const int bm = blockIdx.x * 128;
    const int bn = blockIdx.y * 256;
    const int z  = (MODE == 0) ? blockIdx.z : 0;
    const __bf16* __restrict__ Bw =
        (MODE == 0) ? ((z == 0) ? W0 : (z == 1) ? W1 : W2) : W0;

    const int wr = (wave >> 2) * 64;     // 2 M-waves
    const int wc = (wave & 3) * 64;      // 4 N-waves

    f32x4 acc[4][4];
    #pragma unroll
    for (int i = 0; i < 4; i++)
        #pragma unroll
        for (int j = 0; j < 4; j++)
            acc[i][j] = (f32x4){0.f, 0.f, 0.f, 0.f};

    // staging geometry: unit g covers row g>>3, 16B unit g&7 (source-swizzled)
    const int arow = tid >> 3;
    const int au   = (tid & 7) ^ (arow & 7);    // row&7 invariant under +64
    const __bf16* Ag0 = A  + (size_t)(bm + arow) * ND + au * 8;
    const __bf16* Ag1 = Ag0 + (size_t)64 * ND;
    const __bf16* Bg0 = Bw + (size_t)(bn + arow) * ND + au * 8;
    const __bf16* Bg1 = Bg0 + (size_t)64 * ND;
    const __bf16* Bg2 = Bg0 + (size_t)128 * ND;
    const __bf16* Bg3 = Bg0 + (size_t)192 * ND;

#define STAGE(AS, BS, K0)                                  \
    {                                                      \
        gload16(Ag0 + (K0), (AS) + tid * 8);               \
        gload16(Ag1 + (K0), (AS) + (tid + 512) * 8);       \
        gload16(Bg0 + (K0), (BS) + tid * 8);               \
        gload16(Bg1 + (K0), (BS) + (tid + 512) * 8);       \
        gload16(Bg2 + (K0), (BS) + (tid + 1024) * 8);      \
        gload16(Bg3 + (K0), (BS) + (tid + 1536) * 8);      \
    }

    const int asw = l16 & 7;   // read-side swizzle base (row&7 of fragment row)

#define PHASE(AS, BS, KK)                                                     \
    {                                                                         \
        bf16x8 af[4], bfr[4];                                                 \
        _Pragma("unroll")                                                     \
        for (int i = 0; i < 4; i++)                                           \
            af[i] = *(const bf16x8*)((AS) + (wr + i*16 + l16) * 64            \
                                      + (((KK)*4 + lq) ^ asw) * 8);           \
        _Pragma("unroll")                                                     \
        for (int j = 0; j < 4; j++)                                           \
            bfr[j] = *(const bf16x8*)((BS) + (wc + j*16 + l16) * 64           \
                                       + (((KK)*4 + lq) ^ asw) * 8);          \
        __builtin_amdgcn_s_setprio(1);                                        \
        _Pragma("unroll")                                                     \
        for (int i = 0; i < 4; i++)                                           \
            _Pragma("unroll")                                                 \
            for (int j = 0; j < 4; j++)                                       \
                acc[i][j] = MFMA(af[i], bfr[j], acc[i][j]);                   \
        __builtin_amdgcn_s_setprio(0);                                        \
    }

    STAGE(As0, Bs0, 0)                         // tile 0 -> buf0

    #pragma unroll 1
    for (int t = 0; t < 16; t += 2) {
        // ---- tile t (buf0); prefetch t+1 -> buf1 ----
        if (t + 1 < 16) STAGE(As1, Bs1, (t + 1) * 64)
        if (t + 1 < 16) { asm volatile("s_waitcnt vmcnt(6)" ::: "memory"); }
        else            { asm volatile("s_waitcnt vmcnt(0)" ::: "memory"); }
        __builtin_amdgcn_s_barrier();
        PHASE(As0, Bs0, 0)
        __builtin_amdgcn_s_barrier();
        PHASE(As0, Bs0, 1)
        __builtin_amdgcn_s_barrier();          // buf0 reads complete

        // ---- tile t+1 (buf1); prefetch t+2 -> buf0 ----
        if (t + 2 < 16) STAGE(As0, Bs0, (t + 2) * 64)
        if (t + 2 < 16) { asm volatile("s_waitcnt vmcnt(6)" ::: "memory"); }
        else            { asm volatile("s_waitcnt vmcnt(0)" ::: "memory"); }
        __builtin_amdgcn_s_barrier();
        PHASE(As1, Bs1, 0)
        __builtin_amdgcn_s_barrier();
        PHASE(As1, Bs1, 1)
        __builtin_amdgcn_s_barrier();          // buf1 reads complete
    }
#undef STAGE
#undef PHASE

    if (MODE == 0 && z == 2) {
        // ---- V^T epilogue: LDS transpose (reuse As0 area), coalesced stores
        __bf16* T = As0;
        const int TP = 136;                    // 32 cols x 128 rows, padded
        #pragma unroll 1
        for (int c = 0; c < 8; ++c) {          // 8 chunks of 32 n-cols
            __syncthreads();
            #pragma unroll
            for (int j = 0; j < 4; j++) {
                if (((wc + j * 16) >> 5) != c) continue;
                #pragma unroll
                for (int i = 0; i < 4; i++)
                    #pragma unroll
                    for (int r = 0; r < 4; r++) {
                        int row = wr + i*16 + lq*4 + r;       // m-local (s)
                        int col = wc + j*16 + l16 - c*32;     // chunk-local n
                        T[col * TP + row] = (__bf16)acc[i][j][r];
                    }
            }
            __syncthreads();
            {
                int trow = tid >> 4, tu = tid & 15; // col 0..31, 16B unit
                int gcol = bn + c*32 + trow;        // global n = h*64+dh
                int gs   = bm + tu * 8;             // global m = b*S + s
                bf16x8 val = *(const bf16x8*)&T[trow * TP + tu * 8];
                int hh = gcol >> 6, dh = gcol & 63;
                *(bf16x8*)&O2[(((size_t)(gs >> 11) * NH + hh) * NDH + dh) * NS
                              + (gs & 2047)] = val;
            }
        }
        return;
    }

    #pragma unroll
    for (int i = 0; i < 4; i++) {
        #pragma unroll
        for (int j = 0; j < 4; j++) {
            #pragma unroll
            for (int r = 0; r < 4; r++) {
                int row = bm + wr + i*16 + lq*4 + r;   // m index (b*S + s)
                int col = bn + wc + j*16 + l16;        // n index (d_out)
                float v = acc[i][j][r];
                if (MODE == 1) {
                    Cf[(size_t)row * ND + col] = v;
                } else {
                    if (z == 0) v *= 0.1803368801111204f;  // 1/8 * log2(e)
                    int b = row >> 11, s = row & 2047;
                    int h = col >> 6,  dh = col & 63;
                    __bf16* dst = (z == 0) ? O0 : O1;
                    dst[(((size_t)b*NH + h)*NS + s)*NDH + dh] = (__bf16)v;
                }
            }
        }
    }
}

// ------- causal flash attention (round-21 best: T14 reg-staged, ~86.6 us) ---
__global__ __launch_bounds__(256) void attn_rs(
    const __bf16* __restrict__ Q, const __bf16* __restrict__ K,
    const __bf16* __restrict__ Vt, __bf16* __restrict__ Oa)
{
    __shared__ alignas(16) __bf16 Ks[32*64];   // [kv][dh], source-swizzled
    __shared__ alignas(16) __bf16 Vs[64*32];   // [d][kv],  source-swizzled
    __shared__ float Fs[4][32];

    const int tid  = threadIdx.x;
    const int wave = tid >> 6, lane = tid & 63;
    const int qq   = lane & 31, hi = lane >> 5;

    const int bid = blockIdx.x;                          // 0..1023
    const int jg  = 15 - (bid >> 6);                     // LPT: long first
    const int bh  = (bid & 7) * 8 + ((bid >> 3) & 7);    // XCD-pinned head
    const int j   = 4 * jg + wave;                       // wave's q-block
    const int q0  = 32 * j;
    const int nt  = 4 * jg + 4;                          // staged tiles/block

    const int b = bh >> 4, h = bh & 15;
    const size_t qkb = (size_t)bh * NS * NDH;   // Q,K  [bh][s][dh]
    const size_t vbb = (size_t)bh * NDH * NS;   // Vt   [bh][dh][s]
    float* Fw = Fs[wave];

    // Q fragments (B-operand): col q = qq, k = c*16 + hi*8
    bf16x8 qf[4];
    {
        const __bf16* qr = Q + qkb + (size_t)(q0 + qq) * NDH + hi * 8;
        #pragma unroll
        for (int c = 0; c < 4; c++) qf[c] = *(const bf16x8*)(qr + c * 16);
    }

    f32x16 o0 = (f32x16)0.f, o1 = (f32x16)0.f;  // row q=crow(r), col d=qq(+32)
    float mr = -__builtin_inff(), lsum = 0.f;

    // staging geometry (per thread, one 16B chunk of K and one of V per tile)
    const int kr = tid >> 3, ku = tid & 7;               // K row, LDS unit
    const int vd = tid >> 2, vu = tid & 3;               // V row, LDS unit
    const __bf16* ksrc = K  + qkb + (size_t)kr * NDH + (size_t)((ku ^ (kr & 7)) * 8);
    const __bf16* vsrc = Vt + vbb + (size_t)vd * NS  + (size_t)((vu ^ ((vd >> 1) & 3)) * 8);
    __bf16* kdst = Ks + tid * 8;
    __bf16* vdst = Vs + tid * 8;

    const int vsw = (qq >> 1) & 3;   // V read-side swizzle (same for row qq+32)

    // prologue: load tile 0 into staging registers
    bf16x8 kreg = *(const bf16x8*)ksrc;
    bf16x8 vreg = *(const bf16x8*)vsrc;
    ksrc += 32 * NDH; vsrc += 32;

    #pragma unroll 1
    for (int t = 0; t < nt; ++t) {
        __syncthreads();                 // prior reads done; loads aged
        *(bf16x8*)kdst = kreg;           // write tile t to LDS
        *(bf16x8*)vdst = vreg;
        __syncthreads();                 // tile t visible to all waves

        if (t + 1 < nt) {                // issue tile t+1 loads -> regs
            kreg = *(const bf16x8*)ksrc; // (latency hides under compute)
            vreg = *(const bf16x8*)vsrc;
            ksrc += 32 * NDH; vsrc += 32;
        }

        if (t <= j) {
            // fragment reads (swizzled, conflict-free)
            bf16x8 kf[4], vf[4];
            #pragma unroll
            for (int c = 0; c < 4; c++)
                kf[c] = *(const bf16x8*)(Ks + qq * 64 + ((2 * c + hi) ^ (qq & 7)) * 8);
            vf[0] = *(const bf16x8*)(Vs + qq * 32        + ((hi)     ^ vsw) * 8);
            vf[1] = *(const bf16x8*)(Vs + qq * 32        + ((2 + hi) ^ vsw) * 8);
            vf[2] = *(const bf16x8*)(Vs + (qq + 32) * 32 + ((hi)     ^ vsw) * 8);
            vf[3] = *(const bf16x8*)(Vs + (qq + 32) * 32 + ((2 + hi) ^ vsw) * 8);

            f32x16 s = (f32x16)0.f;
            __builtin_amdgcn_s_setprio(1);
            #pragma unroll
            for (int c = 0; c < 4; c++) s = MFMA32(kf[c], qf[c], s);
            __builtin_amdgcn_s_setprio(0);

            if (t == j) {   // diagonal tile: kv0 == q0
                #pragma unroll
                for (int r = 0; r < 16; r++) {
                    const int crow = (r & 3) + 8 * (r >> 2) + 4 * hi;
                    if (crow > qq) s[r] = -__builtin_inff();
                }
            }

            // max of this lane's 16 scores via v_max3 tree (8 ops)
            float a0 = fmax3(s[0],  s[1],  s[2]);
            float a1 = fmax3(s[3],  s[4],  s[5]);
            float a2 = fmax3(s[6],  s[7],  s[8]);
            float a3 = fmax3(s[9],  s[10], s[11]);
            float a4 = fmax3(s[12], s[13], s[14]);
            float tm = fmaxf(fmax3(a0, a1, a2), fmax3(a3, a4, s[15]));

            if (__any(tm > mr + 8.f)) {
                float rowm = fmaxf(tm, __shfl_xor(tm, 32));
                float mnew = fmaxf(mr, rowm);
                float fac  = exp2f(mr - mnew);
                mr = mnew; lsum *= fac;
                if (lane < 32) Fw[qq] = fac;
                f32x4 f0 = *(const f32x4*)&Fw[4 * hi];
                f32x4 f1 = *(const f32x4*)&Fw[8 + 4 * hi];
                f32x4 f2 = *(const f32x4*)&Fw[16 + 4 * hi];
                f32x4 f3 = *(const f32x4*)&Fw[24 + 4 * hi];
                #pragma unroll
                for (int i = 0; i < 4; i++) {
                    o0[i]      *= f0[i]; o1[i]      *= f0[i];
                    o0[4 + i]  *= f1[i]; o1[4 + i]  *= f1[i];
                    o0[8 + i]  *= f2[i]; o1[8 + i]  *= f2[i];
                    o0[12 + i] *= f3[i]; o1[12 + i] *= f3[i];
                }
            }

            float pv[16]; float psum = 0.f;
            #pragma unroll
            for (int r = 0; r < 16; r++) { pv[r] = exp2f(s[r] - mr); psum += pv[r]; }
            lsum += psum;

            unsigned w0 = cvt_pk_bf16(pv[0],  pv[1]);
            unsigned w1 = cvt_pk_bf16(pv[2],  pv[3]);
            unsigned w2 = cvt_pk_bf16(pv[4],  pv[5]);
            unsigned w3 = cvt_pk_bf16(pv[6],  pv[7]);
            unsigned w4 = cvt_pk_bf16(pv[8],  pv[9]);
            unsigned w5 = cvt_pk_bf16(pv[10], pv[11]);
            unsigned w6 = cvt_pk_bf16(pv[12], pv[13]);
            unsigned w7 = cvt_pk_bf16(pv[14], pv[15]);
            PLSWAP(w0, w2); PLSWAP(w1, w3);
            PLSWAP(w4, w6); PLSWAP(w5, w7);
            bf16x8 pa0 = __builtin_bit_cast(bf16x8, (uint4){w0, w1, w2, w3});
            bf16x8 pa1 = __builtin_bit_cast(bf16x8, (uint4){w4, w5, w6, w7});

            __builtin_amdgcn_s_setprio(1);
            o0 = MFMA32(pa0, vf[0], o0);
            o0 = MFMA32(pa1, vf[1], o0);
            o1 = MFMA32(pa0, vf[2], o1);
            o1 = MFMA32(pa1, vf[3], o1);
            __builtin_amdgcn_s_setprio(0);
        }
    }

    // merge pair-halves of lsum; transport 1/l to o-layout; store
    lsum += __shfl_xor(lsum, 32);
    if (lane < 32) Fw[qq] = 1.f / lsum;
    f32x4 i0 = *(const f32x4*)&Fw[4 * hi];
    f32x4 i1 = *(const f32x4*)&Fw[8 + 4 * hi];
    f32x4 i2 = *(const f32x4*)&Fw[16 + 4 * hi];
    f32x4 i3 = *(const f32x4*)&Fw[24 + 4 * hi];
    __bf16* ob = Oa + ((size_t)b * NS + q0) * ND + h * 64 + qq;
    #pragma unroll
    for (int g2 = 0; g2 < 4; g2++) {
        f32x4 iv = (g2 == 0) ? i0 : (g2 == 1) ? i1 : (g2 == 2) ? i2 : i3;
        #pragma unroll
        for (int i = 0; i < 4; i++) {
            const int row = 8 * g2 + 4 * hi + i;
            ob[(size_t)row * ND]      = (__bf16)(o0[4 * g2 + i] * iv[i]);
            ob[(size_t)row * ND + 32] = (__bf16)(o1[4 * g2 + i] * iv[i]);
        }
    }
}

extern "C" void kernel_launch(void* const* d_in, const int* in_sizes, int n_in,
                              void* d_out, int out_size, void* d_ws, size_t ws_size,
                              hipStream_t stream) {
    const float* x  = (const float*)d_in[0];
    const float* wq = (const float*)d_in[1];
    const float* wk = (const float*)d_in[2];
    const float* wv = (const float*)d_in[3];
    const float* wo = (const float*)d_in[4];
    char* ws = (char*)d_ws;

    __bf16* xb  = (__bf16*)(ws);                      // 16 MB  [M,K]
    __bf16* wqb = (__bf16*)(ws + (16ull << 20));      //  2 MB
    __bf16* wkb = (__bf16*)(ws + (18ull << 20));
    __bf16* wvb = (__bf16*)(ws + (20ull << 20));
    __bf16* wob = (__bf16*)(ws + (22ull << 20));
    __bf16* Qb  = (__bf16*)(ws + (24ull << 20));      // 16 MB [B,H,S,Dh]
    __bf16* Kb  = (__bf16*)(ws + (40ull << 20));      // 16 MB [B,H,S,Dh]
    __bf16* Vtb = (__bf16*)(ws + (56ull << 20));      // 16 MB [B,H,Dh,S]
    __bf16* Ab  = (__bf16*)(ws + (72ull << 20));      // 16 MB [B,S,D]
    float* out  = (float*)d_out;

    // one launch: x (8*2^20) + 4 weights (2^20 each) = 12288 blocks
    cast_all<<<dim3((NM * ND + 4 * ND * ND) / 1024), 256, 0, stream>>>(
        x, wq, wk, wv, wo, xb, wqb, wkb, wvb, wob);

    gemm8p<0><<<dim3(NM/128, ND/256, 3), 512, 0, stream>>>(
        xb, wqb, wkb, wvb, Qb, Kb, Vtb, nullptr);

    attn_rs<<<dim3(1024), 256, 0, stream>>>(Qb, Kb, Vtb, Ab);

    gemm8p<1><<<dim3(NM/128, ND/256), 512, 0, stream>>>(
        Ab, wob, nullptr, nullptr, nullptr, nullptr, nullptr, out);
}